// Round 9
// baseline (279.127 us; speedup 1.0000x reference)
//
#include <hip/hip_runtime.h>

typedef __bf16 bf16;
typedef bf16 bf16x8 __attribute__((ext_vector_type(8)));
typedef bf16 bf16x4 __attribute__((ext_vector_type(4)));
typedef float f32x4 __attribute__((ext_vector_type(4)));

#define MFMA16(a,b,c) __builtin_amdgcn_mfma_f32_16x16x32_bf16(a,b,c,0,0,0)

#define NSEQ 3136
#define CDIM 192

__device__ inline bf16x8 cvt8(float4 a, float4 b) {
  bf16x8 r;
  r[0]=(bf16)a.x; r[1]=(bf16)a.y; r[2]=(bf16)a.z; r[3]=(bf16)a.w;
  r[4]=(bf16)b.x; r[5]=(bf16)b.y; r[6]=(bf16)b.z; r[7]=(bf16)b.w;
  return r;
}

__device__ inline bf16x4 cvt4(float4 a) {
  bf16x4 r;
  r[0]=(bf16)a.x; r[1]=(bf16)a.y; r[2]=(bf16)a.z; r[3]=(bf16)a.w;
  return r;
}

// ---------------- prep: rowsums (blocks 0..255) + weight convert (blocks 256..735) -----------------
__global__ void k_prep(const float* __restrict__ qkv_w, const float* __restrict__ E_w,
                       const float* __restrict__ F_w, const float* __restrict__ proj_w,
                       bf16* __restrict__ qkvw, bf16* __restrict__ EF, bf16* __restrict__ projw,
                       float* __restrict__ rowsums) {
  if (blockIdx.x < 256) {
    __shared__ float red[4];
    int row = blockIdx.x; // 0..255
    const float* src = (row < 128) ? (E_w + (long)row * NSEQ) : (F_w + (long)(row - 128) * NSEQ);
    float s = 0.f;
    for (int i = threadIdx.x; i < 784; i += 256) {
      float4 f = *(const float4*)(src + i * 4);
      s += f.x + f.y + f.z + f.w;
    }
    for (int off = 32; off; off >>= 1) s += __shfl_xor(s, off);
    if ((threadIdx.x & 63) == 0) red[threadIdx.x >> 6] = s;
    __syncthreads();
    if (threadIdx.x == 0) rowsums[row] = red[0] + red[1] + red[2] + red[3];
  } else {
    int i4 = (blockIdx.x - 256) * blockDim.x + threadIdx.x;
    const int tot4 = 950272 / 4;
    const int stride = 480 * 256;
    for (; i4 < tot4; i4 += stride) {
      int i = i4 * 4;
      float4 f;
      bf16* dst;
      if (i < 110592)      { f = *(const float4*)(qkv_w + i);            dst = qkvw + i; }
      else if (i < 512000) { f = *(const float4*)(E_w + (i - 110592));   dst = EF + (i - 110592); }
      else if (i < 913408) { f = *(const float4*)(F_w + (i - 512000));   dst = EF + (i - 110592); }
      else                 { f = *(const float4*)(proj_w + (i - 913408)); dst = projw + (i - 913408); }
      *(bf16x4*)dst = cvt4(f);
    }
  }
}

// ---------------- fused window_reverse+transpose + Q GEMM (v5: Wq PINNED in registers) -------------
// v4 lesson (r8): without a keep-alive, the compiler allocated only 64 VGPR and re-loaded Wq inside
// the MFMA loop. v5 pins the 18 bf16x8 wq values with asm "+v" AFTER phase 1 (loads overlap the
// x staging), making remat illegal. launch_bounds(256,1) = full register freedom.
__launch_bounds__(256, 1)
__global__ void k_xTq(const float* __restrict__ x, const bf16* __restrict__ qkvw,
                      const float* __restrict__ qkv_b, bf16* __restrict__ xmT,
                      bf16* __restrict__ q) {
  __shared__ bf16 tile[64][196];
  int blk = blockIdx.x;
  int b = blk / 49, n0 = (blk % 49) * 64;
  int tid = threadIdx.x;
  int wid = tid >> 6, lane = tid & 63;
  int lrow = lane & 15, hi = lane >> 4, lk = hi * 8;
  // phase 0: issue Wq slab loads (cols 48*wid .. 48*wid+47, full K) -> 18 bf16x8 regs
  bf16x8 wq[18];
  {
    const bf16* wp = qkvw + (long)(48 * wid + lrow) * 192 + lk;
    #pragma unroll
    for (int ks = 0; ks < 6; ks++)
      #pragma unroll
      for (int j = 0; j < 3; j++)
        wq[ks * 3 + j] = *(const bf16x8*)(wp + j * 16 * 192 + ks * 32);
  }
  // phase 1: stage x tile (f32 -> bf16): 64 rows x 48 float4
  for (int e = tid; e < 3072; e += 256) {
    int row = e / 48, c4 = e % 48;
    int n = n0 + row;
    int r = n / 56, cc = n % 56;
    long srcrow = (long)(b * 64 + (r / 7) * 8 + (cc / 7)) * 49 + (r % 7) * 7 + (cc % 7);
    float4 f = *(const float4*)(x + srcrow * 192 + c4 * 4);
    *(bf16x4*)&tile[row][c4 * 4] = cvt4(f);
  }
  // pin wq in VGPRs: "+v" makes the values unrematerializable from here on
  #pragma unroll
  for (int i = 0; i < 18; i++)
    asm volatile("" : "+v"(*(f32x4*)&wq[i]));
  __syncthreads();
  // phase 2: MFMA — wave covers all 64 rows x its 48 cols; B operands are pinned registers
  f32x4 zero = {0.f, 0.f, 0.f, 0.f};
  f32x4 acc[4][3];
  for (int m = 0; m < 4; m++) for (int j = 0; j < 3; j++) acc[m][j] = zero;
  #pragma unroll
  for (int ks = 0; ks < 6; ks++) {
    bf16x8 af[4];
    #pragma unroll
    for (int m = 0; m < 4; m++) af[m] = *(bf16x8*)&tile[16 * m + lrow][ks * 32 + lk];
    #pragma unroll
    for (int m = 0; m < 4; m++)
      #pragma unroll
      for (int j = 0; j < 3; j++)
        acc[m][j] = MFMA16(af[m], wq[ks * 3 + j], acc[m][j]);
  }
  // phase 2b: transpose writes (reads tile): 8 consecutive threads -> 128B contiguous per c-row
  for (int e = tid; e < 1536; e += 256) {
    int c = e >> 3, k = e & 7;
    bf16x8 v;
    for (int jj = 0; jj < 8; jj++) v[jj] = tile[k * 8 + jj][c];
    *(bf16x8*)(xmT + ((long)b * 192 + c) * NSEQ + n0 + k * 8) = v;
  }
  __syncthreads();   // all tile reads (MFMA + transpose) complete
  // phase 3: acc -> tile as bf16 (bias + scale); wave writes rows 0..63 of its col slab
  const float scale = 0.17677669529663687f; // 1/sqrt(32)
  for (int m = 0; m < 4; m++) for (int j = 0; j < 3; j++) {
    int c = 48 * wid + 16 * j + lrow;
    float bias = qkv_b[c];
    for (int rr = 0; rr < 4; rr++)
      tile[16 * m + hi * 4 + rr][c] = (bf16)((acc[m][j][rr] + bias) * scale);
  }
  __syncthreads();
  // phase 4: coalesced q stores: 24 consecutive lanes = 384B contiguous per row
  for (int e = tid; e < 1536; e += 256) {
    int row = e / 24, ch = e % 24;
    bf16x4 lo = *(bf16x4*)&tile[row][ch * 8];
    bf16x4 hh = *(bf16x4*)&tile[row][ch * 8 + 4];
    bf16x8 v;
    v[0]=lo[0]; v[1]=lo[1]; v[2]=lo[2]; v[3]=lo[3];
    v[4]=hh[0]; v[5]=hh[1]; v[6]=hh[2]; v[7]=hh[3];
    *(bf16x8*)(q + ((long)b * NSEQ + n0 + row) * 192 + ch * 8) = v;
  }
}

// ---------------- xlow GEMM: one block per (b, K-slice); full 256x192 tile, K=448 ------------------
__launch_bounds__(512)
__global__ void k_xlow(const bf16* __restrict__ EF, const bf16* __restrict__ xmT,
                       float* __restrict__ partial) {
  __shared__ bf16 As[256][72];
  __shared__ bf16 Bs[192][72];
  int idx = blockIdx.x;          // b*7 + s
  int s = idx % 7, b = idx / 7;
  int kbase = s * 448;
  int tid = threadIdx.x;
  int wid = tid >> 6, lane = tid & 63;
  int wm = wid >> 2, wn = wid & 3;        // 2 x 4 wave grid
  int lrow = lane & 15, hi = lane >> 4, lk = hi * 8;
  f32x4 zero = {0.f, 0.f, 0.f, 0.f};
  f32x4 acc[8][3];
  for (int i = 0; i < 8; i++) for (int j = 0; j < 3; j++) acc[i][j] = zero;
  for (int k0 = 0; k0 < 448; k0 += 64) {
    for (int i = 0; i < 4; i++) {
      int unit = i * 512 + tid;
      int row = unit >> 3, koff = (unit & 7) * 8;
      *(bf16x8*)&As[row][koff] = *(const bf16x8*)(EF + (long)row * NSEQ + kbase + k0 + koff);
    }
    for (int i = 0; i < 3; i++) {
      int unit = i * 512 + tid;
      int row = unit >> 3, koff = (unit & 7) * 8;
      *(bf16x8*)&Bs[row][koff] = *(const bf16x8*)(xmT + ((long)b * 192 + row) * NSEQ + kbase + k0 + koff);
    }
    __syncthreads();
    for (int ks = 0; ks < 2; ks++) {
      bf16x8 af[8], bfv[3];
      for (int i = 0; i < 8; i++) af[i]  = *(bf16x8*)&As[wm * 128 + 16 * i + lrow][ks * 32 + lk];
      for (int j = 0; j < 3; j++) bfv[j] = *(bf16x8*)&Bs[wn * 48 + 16 * j + lrow][ks * 32 + lk];
      for (int i = 0; i < 8; i++) for (int j = 0; j < 3; j++) acc[i][j] = MFMA16(af[i], bfv[j], acc[i][j]);
    }
    __syncthreads();
  }
  float* P = partial + (long)idx * 49152;  // 256 x 192 f32
  for (int i = 0; i < 8; i++) for (int j = 0; j < 3; j++) for (int rr = 0; rr < 4; rr++) {
    int rl = wm * 128 + 16 * i + hi * 4 + rr;
    int cl = wn * 48 + 16 * j + lrow;
    P[rl * 192 + cl] = acc[i][j][rr];
  }
}

// ---------------- reduce 7 split-K partials -> el_fl (b,256,192) bf16 (linear, vectorized) ---------
__global__ void k_reduce(const float* __restrict__ partial, bf16* __restrict__ el_fl) {
  int blk = blockIdx.x;          // 32 b x 48 chunks
  int b = blk / 48, ch = blk % 48;
  long e = (long)ch * 1024 + threadIdx.x * 4;   // 0..49151
  const float* P = partial + (long)b * 7 * 49152 + e;
  float4 sum = {0.f, 0.f, 0.f, 0.f};
  for (int s = 0; s < 7; s++) {
    float4 f = *(const float4*)(P + (long)s * 49152);
    sum.x += f.x; sum.y += f.y; sum.z += f.z; sum.w += f.w;
  }
  *(bf16x4*)(el_fl + (long)b * 49152 + e) = cvt4(sum);
}

// ---------------- low-rank proj: k_lowH = el@Wk^T + bias (HEAD-MAJOR) ; v_lowT = Wv@fl^T + bias ----
__launch_bounds__(256)
__global__ void k_lowproj(const bf16* __restrict__ el_fl, const bf16* __restrict__ qkvw,
                          const float* __restrict__ qkv_b, const float* __restrict__ E_b,
                          const float* __restrict__ F_b, const float* __restrict__ rowsums,
                          bf16* __restrict__ k_lowH, bf16* __restrict__ v_lowT) {
  __shared__ bf16 As[64][200];
  __shared__ bf16 Bs[64][200];
  int idx = blockIdx.x;
  int b = idx / 12, rem = idx % 12;
  int type = rem / 6; rem %= 6;
  int bm, bn;
  if (type == 0) { bm = rem / 3; bn = rem % 3; }
  else           { bm = rem / 2; bn = rem % 2; }
  int m0 = bm * 64, n0 = bn * 64;
  int tid = threadIdx.x;
  int wid = tid >> 6, lane = tid & 63;
  int wm = wid >> 1, wn = wid & 1;
  int lrow = lane & 15, lk = (lane >> 4) * 8;
  int srow = tid >> 2, skoff = (tid & 3) * 16;
  const bf16* Ap; const bf16* Bp;
  if (type == 0) {
    Ap = el_fl + ((long)b * 256 + m0 + srow) * 192 + skoff;
    Bp = qkvw + (long)(192 + n0 + srow) * 192 + skoff;
  } else {
    Ap = qkvw + (long)(384 + m0 + srow) * 192 + skoff;
    Bp = el_fl + ((long)b * 256 + 128 + n0 + srow) * 192 + skoff;
  }
  for (int kk = 0; kk < 192; kk += 64) {
    *(bf16x8*)&As[srow][kk + skoff]     = *(const bf16x8*)(Ap + kk);
    *(bf16x8*)&As[srow][kk + skoff + 8] = *(const bf16x8*)(Ap + kk + 8);
    *(bf16x8*)&Bs[srow][kk + skoff]     = *(const bf16x8*)(Bp + kk);
    *(bf16x8*)&Bs[srow][kk + skoff + 8] = *(const bf16x8*)(Bp + kk + 8);
  }
  __syncthreads();
  f32x4 zero = {0.f, 0.f, 0.f, 0.f};
  f32x4 acc[2][2];
  for (int i = 0; i < 2; i++) for (int j = 0; j < 2; j++) acc[i][j] = zero;
  for (int ks = 0; ks < 6; ks++) {
    bf16x8 af[2], bfv[2];
    for (int i = 0; i < 2; i++) af[i]  = *(bf16x8*)&As[wm * 32 + 16 * i + lrow][ks * 32 + lk];
    for (int j = 0; j < 2; j++) bfv[j] = *(bf16x8*)&Bs[wn * 32 + 16 * j + lrow][ks * 32 + lk];
    for (int i = 0; i < 2; i++) for (int j = 0; j < 2; j++) acc[i][j] = MFMA16(af[i], bfv[j], acc[i][j]);
  }
  if (type == 0) {
    for (int i = 0; i < 2; i++) for (int j = 0; j < 2; j++) for (int rr = 0; rr < 4; rr++) {
      int kr = m0 + wm * 32 + 16 * i + (lane >> 4) * 4 + rr;
      int c = n0 + wn * 32 + 16 * j + lrow;
      float v = acc[i][j][rr] + rowsums[kr] * qkv_b[192 + c] + E_b[kr];
      // head-major: [b][h][128][32]
      k_lowH[(((long)b * 6 + (c >> 5)) * 128 + kr) * 32 + (c & 31)] = (bf16)v;
    }
  } else {
    for (int i = 0; i < 2; i++) for (int j = 0; j < 2; j++) for (int rr = 0; rr < 4; rr++) {
      int c = m0 + wm * 32 + 16 * i + (lane >> 4) * 4 + rr;
      int kr = n0 + wn * 32 + 16 * j + lrow;
      float v = acc[i][j][rr] + rowsums[128 + kr] * qkv_b[384 + c] + F_b[kr];
      v_lowT[((long)b * 192 + c) * 128 + kr] = (bf16)v;
    }
  }
}

// ---------------- fused attention: swapped QK^T -> in-register softmax -----------------------------
__launch_bounds__(256)
__global__ void k_attn(const bf16* __restrict__ q, const bf16* __restrict__ k_lowH,
                       const bf16* __restrict__ v_lowT, bf16* __restrict__ out_att) {
  __shared__ bf16 Ks[128][40];
  __shared__ bf16 Vs[32][136];
  __shared__ bf16 Ps[4][16][136];
  int idx = blockIdx.x;
  int nt = idx % 49, bh = idx / 49;
  int h = bh % 6, b = bh / 6;
  int n0 = nt * 64;
  int tid = threadIdx.x;
  int wid = tid >> 6, lane = tid & 63;
  int lrow = lane & 15, hi = lane >> 4, lk = hi * 8;
  {
    // head-major K: fully contiguous 8KB block
    int row = tid >> 1, koff = (tid & 1) * 16;
    const bf16* src = k_lowH + (((long)b * 6 + h) * 128 + row) * 32 + koff;
    *(bf16x8*)&Ks[row][koff] = *(const bf16x8*)src;
    *(bf16x8*)&Ks[row][koff + 8] = *(const bf16x8*)(src + 8);
  }
  {
    int row = tid >> 3, koff = (tid & 7) * 16;
    const bf16* src = v_lowT + ((long)b * 192 + h * 32 + row) * 128 + koff;
    *(bf16x8*)&Vs[row][koff] = *(const bf16x8*)src;
    *(bf16x8*)&Vs[row][koff + 8] = *(const bf16x8*)(src + 8);
  }
  int nrow = n0 + wid * 16 + lrow;
  bf16x8 qf = *(const bf16x8*)(q + ((long)b * NSEQ + nrow) * 192 + h * 32 + lk);
  __syncthreads();
  f32x4 zero = {0.f, 0.f, 0.f, 0.f};
  f32x4 s[8];
  // swapped: D[k][q] — lane's q-row = lrow (fixed), k = 16f + hi*4 + rr
  for (int f = 0; f < 8; f++) {
    bf16x8 kf = *(bf16x8*)&Ks[16 * f + lrow][lk];
    s[f] = MFMA16(kf, qf, zero);
  }
  float m = s[0][0];
  for (int f = 0; f < 8; f++) for (int rr = 0; rr < 4; rr++) m = fmaxf(m, s[f][rr]);
  m = fmaxf(m, __shfl_xor(m, 16));
  m = fmaxf(m, __shfl_xor(m, 32));
  float sum = 0.f;
  for (int f = 0; f < 8; f++) for (int rr = 0; rr < 4; rr++) {
    float p = __expf(s[f][rr] - m);
    s[f][rr] = p; sum += p;
  }
  sum += __shfl_xor(sum, 16);
  sum += __shfl_xor(sum, 32);
  float inv = 1.0f / sum;
  for (int f = 0; f < 8; f++) {
    bf16x4 pv;
    for (int rr = 0; rr < 4; rr++) pv[rr] = (bf16)(s[f][rr] * inv);
    *(bf16x4*)&Ps[wid][lrow][16 * f + hi * 4] = pv;
  }
  __syncthreads();
  f32x4 o[2];
  o[0] = zero; o[1] = zero;
  for (int ks = 0; ks < 4; ks++) {
    bf16x8 pf = *(bf16x8*)&Ps[wid][lrow][ks * 32 + lk];
    for (int j = 0; j < 2; j++) {
      bf16x8 vf = *(bf16x8*)&Vs[16 * j + lrow][ks * 32 + lk];
      o[j] = MFMA16(pf, vf, o[j]);
    }
  }
  for (int j = 0; j < 2; j++) for (int rr = 0; rr < 4; rr++) {
    int nn = n0 + wid * 16 + hi * 4 + rr;
    out_att[((long)b * NSEQ + nn) * 192 + h * 32 + 16 * j + lrow] = (bf16)o[j][rr];
  }
}

// ---------------- proj GEMM full-N: out(128 rows, all 192 cols) fp32; projw LDS-resident -----------
__launch_bounds__(256)
__global__ void k_proj(const bf16* __restrict__ oa, const bf16* __restrict__ projw,
                       const float* __restrict__ proj_b, float* __restrict__ out) {
  __shared__ bf16 As[128][104];
  __shared__ bf16 Bs[192][200];
  long g0 = (long)blockIdx.x * 128;
  int tid = threadIdx.x;
  int wid = tid >> 6, lane = tid & 63;
  int lrow = lane & 15, lk = (lane >> 4) * 8;
  {
    int koff = (tid & 3) * 48;
    for (int r0 = 0; r0 < 192; r0 += 64) {
      int row = r0 + (tid >> 2);
      const bf16* Bp = projw + (long)row * 192 + koff;
      for (int m = 0; m < 6; m++)
        *(bf16x8*)&Bs[row][koff + 8 * m] = *(const bf16x8*)(Bp + 8 * m);
    }
  }
  int arow = tid >> 1, half = tid & 1;
  const bf16* Ap = oa + (g0 + arow) * 192 + half * 48;
  f32x4 zero = {0.f, 0.f, 0.f, 0.f};
  f32x4 acc[2][12];
  for (int i = 0; i < 2; i++) for (int j = 0; j < 12; j++) acc[i][j] = zero;
  for (int k0 = 0; k0 < 192; k0 += 96) {
    for (int m = 0; m < 6; m++)
      *(bf16x8*)&As[arow][half * 48 + 8 * m] = *(const bf16x8*)(Ap + k0 + 8 * m);
    __syncthreads();
    for (int ks = 0; ks < 3; ks++) {
      bf16x8 af[2];
      for (int i = 0; i < 2; i++) af[i] = *(bf16x8*)&As[wid * 32 + 16 * i + lrow][ks * 32 + lk];
      for (int j = 0; j < 12; j++) {
        bf16x8 bv = *(bf16x8*)&Bs[16 * j + lrow][k0 + ks * 32 + lk];
        acc[0][j] = MFMA16(af[0], bv, acc[0][j]);
        acc[1][j] = MFMA16(af[1], bv, acc[1][j]);
      }
    }
    __syncthreads();
  }
  for (int i = 0; i < 2; i++) for (int j = 0; j < 12; j++) for (int rr = 0; rr < 4; rr++) {
    long grow = g0 + wid * 32 + 16 * i + (lane >> 4) * 4 + rr;
    int c = 16 * j + lrow;
    out[grow * 192 + c] = acc[i][j][rr] + proj_b[c];
  }
}

extern "C" void kernel_launch(void* const* d_in, const int* in_sizes, int n_in,
                              void* d_out, int out_size, void* d_ws, size_t ws_size,
                              hipStream_t stream) {
  const float* x      = (const float*)d_in[0];
  const float* qkv_w  = (const float*)d_in[1];
  const float* qkv_b  = (const float*)d_in[2];
  const float* E_w    = (const float*)d_in[3];
  const float* E_b    = (const float*)d_in[4];
  const float* F_w    = (const float*)d_in[5];
  const float* F_b    = (const float*)d_in[6];
  const float* proj_w = (const float*)d_in[7];
  const float* proj_b = (const float*)d_in[8];
  float* out = (float*)d_out;

  char* ws = (char*)d_ws;
  size_t off = 0;
  auto alloc = [&](size_t bytes) { char* p = ws + off; off += (bytes + 255) & ~(size_t)255; return p; };
  bf16* qkvw     = (bf16*)alloc((size_t)110592 * 2);
  bf16* EF       = (bf16*)alloc((size_t)802816 * 2);
  bf16* projw    = (bf16*)alloc((size_t)36864 * 2);
  float* rowsums = (float*)alloc((size_t)256 * 4);
  bf16* xmT      = (bf16*)alloc((size_t)32 * 192 * NSEQ * 2);   // reused as out_att after xlow
  bf16* q        = (bf16*)alloc((size_t)32 * NSEQ * 192 * 2);   // live xTq -> attn (no alias)
  float* partial = (float*)alloc((size_t)224 * 49152 * 4);      // 44 MB
  bf16* el_fl    = (bf16*)alloc((size_t)32 * 256 * 192 * 2);
  bf16* k_lowH   = (bf16*)alloc((size_t)32 * 6 * 128 * 32 * 2);
  bf16* v_lowT   = (bf16*)alloc((size_t)32 * 192 * 128 * 2);
  bf16* out_att  = xmT;

  k_prep<<<dim3(736), dim3(256), 0, stream>>>(qkv_w, E_w, F_w, proj_w, qkvw, EF, projw, rowsums);
  k_xTq<<<dim3(32 * 49), dim3(256), 0, stream>>>(x, qkvw, qkv_b, xmT, q);
  k_xlow<<<dim3(224), dim3(512), 0, stream>>>(EF, xmT, partial);
  k_reduce<<<dim3(1536), dim3(256), 0, stream>>>(partial, el_fl);
  k_lowproj<<<dim3(384), dim3(256), 0, stream>>>(el_fl, qkvw, qkv_b, E_b, F_b, rowsums, k_lowH, v_lowT);
  k_attn<<<dim3(32 * 6 * 49), dim3(256), 0, stream>>>(q, k_lowH, v_lowT, out_att);
  k_proj<<<dim3(784), dim3(256), 0, stream>>>(out_att, projw, proj_b, out);
}

// Round 10
// 264.340 us; speedup vs baseline: 1.0559x; 1.0559x over previous
//
#include <hip/hip_runtime.h>

typedef __bf16 bf16;
typedef bf16 bf16x8 __attribute__((ext_vector_type(8)));
typedef bf16 bf16x4 __attribute__((ext_vector_type(4)));
typedef float f32x4 __attribute__((ext_vector_type(4)));

#define MFMA16(a,b,c) __builtin_amdgcn_mfma_f32_16x16x32_bf16(a,b,c,0,0,0)

#define NSEQ 3136
#define CDIM 192

__device__ inline bf16x8 cvt8(float4 a, float4 b) {
  bf16x8 r;
  r[0]=(bf16)a.x; r[1]=(bf16)a.y; r[2]=(bf16)a.z; r[3]=(bf16)a.w;
  r[4]=(bf16)b.x; r[5]=(bf16)b.y; r[6]=(bf16)b.z; r[7]=(bf16)b.w;
  return r;
}

__device__ inline bf16x4 cvt4(float4 a) {
  bf16x4 r;
  r[0]=(bf16)a.x; r[1]=(bf16)a.y; r[2]=(bf16)a.z; r[3]=(bf16)a.w;
  return r;
}

// ---------------- prep: rowsums (blocks 0..255) + weight convert (blocks 256..735) -----------------
__global__ void k_prep(const float* __restrict__ qkv_w, const float* __restrict__ E_w,
                       const float* __restrict__ F_w, const float* __restrict__ proj_w,
                       bf16* __restrict__ qkvw, bf16* __restrict__ EF, bf16* __restrict__ projw,
                       float* __restrict__ rowsums) {
  if (blockIdx.x < 256) {
    __shared__ float red[4];
    int row = blockIdx.x; // 0..255
    const float* src = (row < 128) ? (E_w + (long)row * NSEQ) : (F_w + (long)(row - 128) * NSEQ);
    float s = 0.f;
    for (int i = threadIdx.x; i < 784; i += 256) {
      float4 f = *(const float4*)(src + i * 4);
      s += f.x + f.y + f.z + f.w;
    }
    for (int off = 32; off; off >>= 1) s += __shfl_xor(s, off);
    if ((threadIdx.x & 63) == 0) red[threadIdx.x >> 6] = s;
    __syncthreads();
    if (threadIdx.x == 0) rowsums[row] = red[0] + red[1] + red[2] + red[3];
  } else {
    int i4 = (blockIdx.x - 256) * blockDim.x + threadIdx.x;
    const int tot4 = 950272 / 4;
    const int stride = 480 * 256;
    for (; i4 < tot4; i4 += stride) {
      int i = i4 * 4;
      float4 f;
      bf16* dst;
      if (i < 110592)      { f = *(const float4*)(qkv_w + i);            dst = qkvw + i; }
      else if (i < 512000) { f = *(const float4*)(E_w + (i - 110592));   dst = EF + (i - 110592); }
      else if (i < 913408) { f = *(const float4*)(F_w + (i - 512000));   dst = EF + (i - 110592); }
      else                 { f = *(const float4*)(proj_w + (i - 913408)); dst = projw + (i - 913408); }
      *(bf16x4*)dst = cvt4(f);
    }
  }
}

// ---------------- fused window_reverse+transpose + Q GEMM (v6: r8 base + cheap addressing) ---------
// r9 lesson: register-pinning failed (VGPR 72, regressed) — abandoned. r8 base (VGPR 64, 56.5us)
// + srcrow precompute in LDS: phase-1 address math cut ~6x (was 8 const-divisions per gather iter).
__global__ void k_xTq(const float* __restrict__ x, const bf16* __restrict__ qkvw,
                      const float* __restrict__ qkv_b, bf16* __restrict__ xmT,
                      bf16* __restrict__ q) {
  __shared__ bf16 tile[64][196];
  __shared__ long srow_l[64];
  int blk = blockIdx.x;
  int b = blk / 49, n0 = (blk % 49) * 64;
  int tid = threadIdx.x;
  int wid = tid >> 6, lane = tid & 63;
  int lrow = lane & 15, hi = lane >> 4, lk = hi * 8;
  // phase 0: issue Wq slab loads (cols 48*wid .. 48*wid+47, full K) -> 18 bf16x8 regs
  bf16x8 wq[18];
  {
    const bf16* wp = qkvw + (long)(48 * wid + lrow) * 192 + lk;
    #pragma unroll
    for (int ks = 0; ks < 6; ks++)
      #pragma unroll
      for (int j = 0; j < 3; j++)
        wq[ks * 3 + j] = *(const bf16x8*)(wp + j * 16 * 192 + ks * 32);
  }
  // phase 0b: srcrow precompute (one div-chain per row, done once)
  if (tid < 64) {
    int n = n0 + tid;
    int r = n / 56, cc = n % 56;
    srow_l[tid] = ((long)(b * 64 + (r / 7) * 8 + (cc / 7)) * 49 + (r % 7) * 7 + (cc % 7)) * 192;
  }
  __syncthreads();
  // phase 1: stage x tile (f32 -> bf16): 192 threads, 16 iters x 4 rows, 768B-contiguous per row
  if (tid < 192) {
    int c4 = tid % 48, rq = tid / 48;   // hoisted out of the loop
    #pragma unroll 4
    for (int i = 0; i < 16; i++) {
      int row = i * 4 + rq;
      float4 f = *(const float4*)(x + srow_l[row] + c4 * 4);
      *(bf16x4*)&tile[row][c4 * 4] = cvt4(f);
    }
  }
  __syncthreads();
  // phase 2: MFMA — wave covers all 64 rows x its 48 cols
  f32x4 zero = {0.f, 0.f, 0.f, 0.f};
  f32x4 acc[4][3];
  for (int m = 0; m < 4; m++) for (int j = 0; j < 3; j++) acc[m][j] = zero;
  #pragma unroll
  for (int ks = 0; ks < 6; ks++) {
    bf16x8 af[4];
    #pragma unroll
    for (int m = 0; m < 4; m++) af[m] = *(bf16x8*)&tile[16 * m + lrow][ks * 32 + lk];
    #pragma unroll
    for (int m = 0; m < 4; m++)
      #pragma unroll
      for (int j = 0; j < 3; j++)
        acc[m][j] = MFMA16(af[m], wq[ks * 3 + j], acc[m][j]);
  }
  // phase 2b: transpose writes (reads tile): 8 consecutive threads -> 128B contiguous per c-row
  for (int e = tid; e < 1536; e += 256) {
    int c = e >> 3, k = e & 7;
    bf16x8 v;
    for (int jj = 0; jj < 8; jj++) v[jj] = tile[k * 8 + jj][c];
    *(bf16x8*)(xmT + ((long)b * 192 + c) * NSEQ + n0 + k * 8) = v;
  }
  __syncthreads();   // all tile reads (MFMA + transpose) complete
  // phase 3: acc -> tile as bf16 (bias + scale); wave writes rows 0..63 of its col slab
  const float scale = 0.17677669529663687f; // 1/sqrt(32)
  for (int m = 0; m < 4; m++) for (int j = 0; j < 3; j++) {
    int c = 48 * wid + 16 * j + lrow;
    float bias = qkv_b[c];
    for (int rr = 0; rr < 4; rr++)
      tile[16 * m + hi * 4 + rr][c] = (bf16)((acc[m][j][rr] + bias) * scale);
  }
  __syncthreads();
  // phase 4: coalesced q stores: 24 consecutive lanes = 384B contiguous per row
  for (int e = tid; e < 1536; e += 256) {
    int row = e / 24, ch = e % 24;
    bf16x4 lo = *(bf16x4*)&tile[row][ch * 8];
    bf16x4 hh = *(bf16x4*)&tile[row][ch * 8 + 4];
    bf16x8 v;
    v[0]=lo[0]; v[1]=lo[1]; v[2]=lo[2]; v[3]=lo[3];
    v[4]=hh[0]; v[5]=hh[1]; v[6]=hh[2]; v[7]=hh[3];
    *(bf16x8*)(q + ((long)b * NSEQ + n0 + row) * 192 + ch * 8) = v;
  }
}

// ---------------- xlow GEMM: one block per (b, K-slice); full 256x192 tile, K=448 ------------------
__launch_bounds__(512)
__global__ void k_xlow(const bf16* __restrict__ EF, const bf16* __restrict__ xmT,
                       float* __restrict__ partial) {
  __shared__ bf16 As[256][72];
  __shared__ bf16 Bs[192][72];
  int idx = blockIdx.x;          // b*7 + s
  int s = idx % 7, b = idx / 7;
  int kbase = s * 448;
  int tid = threadIdx.x;
  int wid = tid >> 6, lane = tid & 63;
  int wm = wid >> 2, wn = wid & 3;        // 2 x 4 wave grid
  int lrow = lane & 15, hi = lane >> 4, lk = hi * 8;
  f32x4 zero = {0.f, 0.f, 0.f, 0.f};
  f32x4 acc[8][3];
  for (int i = 0; i < 8; i++) for (int j = 0; j < 3; j++) acc[i][j] = zero;
  for (int k0 = 0; k0 < 448; k0 += 64) {
    for (int i = 0; i < 4; i++) {
      int unit = i * 512 + tid;
      int row = unit >> 3, koff = (unit & 7) * 8;
      *(bf16x8*)&As[row][koff] = *(const bf16x8*)(EF + (long)row * NSEQ + kbase + k0 + koff);
    }
    for (int i = 0; i < 3; i++) {
      int unit = i * 512 + tid;
      int row = unit >> 3, koff = (unit & 7) * 8;
      *(bf16x8*)&Bs[row][koff] = *(const bf16x8*)(xmT + ((long)b * 192 + row) * NSEQ + kbase + k0 + koff);
    }
    __syncthreads();
    for (int ks = 0; ks < 2; ks++) {
      bf16x8 af[8], bfv[3];
      for (int i = 0; i < 8; i++) af[i]  = *(bf16x8*)&As[wm * 128 + 16 * i + lrow][ks * 32 + lk];
      for (int j = 0; j < 3; j++) bfv[j] = *(bf16x8*)&Bs[wn * 48 + 16 * j + lrow][ks * 32 + lk];
      for (int i = 0; i < 8; i++) for (int j = 0; j < 3; j++) acc[i][j] = MFMA16(af[i], bfv[j], acc[i][j]);
    }
    __syncthreads();
  }
  float* P = partial + (long)idx * 49152;  // 256 x 192 f32
  for (int i = 0; i < 8; i++) for (int j = 0; j < 3; j++) for (int rr = 0; rr < 4; rr++) {
    int rl = wm * 128 + 16 * i + hi * 4 + rr;
    int cl = wn * 48 + 16 * j + lrow;
    P[rl * 192 + cl] = acc[i][j][rr];
  }
}

// ---------------- reduce 7 split-K partials -> el_fl (b,256,192) bf16 (linear, vectorized) ---------
__global__ void k_reduce(const float* __restrict__ partial, bf16* __restrict__ el_fl) {
  int blk = blockIdx.x;          // 32 b x 48 chunks
  int b = blk / 48, ch = blk % 48;
  long e = (long)ch * 1024 + threadIdx.x * 4;   // 0..49151
  const float* P = partial + (long)b * 7 * 49152 + e;
  float4 sum = {0.f, 0.f, 0.f, 0.f};
  for (int s = 0; s < 7; s++) {
    float4 f = *(const float4*)(P + (long)s * 49152);
    sum.x += f.x; sum.y += f.y; sum.z += f.z; sum.w += f.w;
  }
  *(bf16x4*)(el_fl + (long)b * 49152 + e) = cvt4(sum);
}

// ---------------- low-rank proj: k_lowH = el@Wk^T + bias (HEAD-MAJOR) ; v_lowT = Wv@fl^T + bias ----
__launch_bounds__(256)
__global__ void k_lowproj(const bf16* __restrict__ el_fl, const bf16* __restrict__ qkvw,
                          const float* __restrict__ qkv_b, const float* __restrict__ E_b,
                          const float* __restrict__ F_b, const float* __restrict__ rowsums,
                          bf16* __restrict__ k_lowH, bf16* __restrict__ v_lowT) {
  __shared__ bf16 As[64][200];
  __shared__ bf16 Bs[64][200];
  int idx = blockIdx.x;
  int b = idx / 12, rem = idx % 12;
  int type = rem / 6; rem %= 6;
  int bm, bn;
  if (type == 0) { bm = rem / 3; bn = rem % 3; }
  else           { bm = rem / 2; bn = rem % 2; }
  int m0 = bm * 64, n0 = bn * 64;
  int tid = threadIdx.x;
  int wid = tid >> 6, lane = tid & 63;
  int wm = wid >> 1, wn = wid & 1;
  int lrow = lane & 15, lk = (lane >> 4) * 8;
  int srow = tid >> 2, skoff = (tid & 3) * 16;
  const bf16* Ap; const bf16* Bp;
  if (type == 0) {
    Ap = el_fl + ((long)b * 256 + m0 + srow) * 192 + skoff;
    Bp = qkvw + (long)(192 + n0 + srow) * 192 + skoff;
  } else {
    Ap = qkvw + (long)(384 + m0 + srow) * 192 + skoff;
    Bp = el_fl + ((long)b * 256 + 128 + n0 + srow) * 192 + skoff;
  }
  for (int kk = 0; kk < 192; kk += 64) {
    *(bf16x8*)&As[srow][kk + skoff]     = *(const bf16x8*)(Ap + kk);
    *(bf16x8*)&As[srow][kk + skoff + 8] = *(const bf16x8*)(Ap + kk + 8);
    *(bf16x8*)&Bs[srow][kk + skoff]     = *(const bf16x8*)(Bp + kk);
    *(bf16x8*)&Bs[srow][kk + skoff + 8] = *(const bf16x8*)(Bp + kk + 8);
  }
  __syncthreads();
  f32x4 zero = {0.f, 0.f, 0.f, 0.f};
  f32x4 acc[2][2];
  for (int i = 0; i < 2; i++) for (int j = 0; j < 2; j++) acc[i][j] = zero;
  for (int ks = 0; ks < 6; ks++) {
    bf16x8 af[2], bfv[2];
    for (int i = 0; i < 2; i++) af[i]  = *(bf16x8*)&As[wm * 32 + 16 * i + lrow][ks * 32 + lk];
    for (int j = 0; j < 2; j++) bfv[j] = *(bf16x8*)&Bs[wn * 32 + 16 * j + lrow][ks * 32 + lk];
    for (int i = 0; i < 2; i++) for (int j = 0; j < 2; j++) acc[i][j] = MFMA16(af[i], bfv[j], acc[i][j]);
  }
  if (type == 0) {
    for (int i = 0; i < 2; i++) for (int j = 0; j < 2; j++) for (int rr = 0; rr < 4; rr++) {
      int kr = m0 + wm * 32 + 16 * i + (lane >> 4) * 4 + rr;
      int c = n0 + wn * 32 + 16 * j + lrow;
      float v = acc[i][j][rr] + rowsums[kr] * qkv_b[192 + c] + E_b[kr];
      // head-major: [b][h][128][32]
      k_lowH[(((long)b * 6 + (c >> 5)) * 128 + kr) * 32 + (c & 31)] = (bf16)v;
    }
  } else {
    for (int i = 0; i < 2; i++) for (int j = 0; j < 2; j++) for (int rr = 0; rr < 4; rr++) {
      int c = m0 + wm * 32 + 16 * i + (lane >> 4) * 4 + rr;
      int kr = n0 + wn * 32 + 16 * j + lrow;
      float v = acc[i][j][rr] + rowsums[128 + kr] * qkv_b[384 + c] + F_b[kr];
      v_lowT[((long)b * 192 + c) * 128 + kr] = (bf16)v;
    }
  }
}

// ---------------- fused attention: swapped QK^T, in-register softmax, coalesced O store ------------
__launch_bounds__(256)
__global__ void k_attn(const bf16* __restrict__ q, const bf16* __restrict__ k_lowH,
                       const bf16* __restrict__ v_lowT, bf16* __restrict__ out_att) {
  __shared__ bf16 Ks[128][40];
  __shared__ bf16 Vs[32][136];
  __shared__ bf16 Ps[4][16][136];
  int idx = blockIdx.x;
  int nt = idx % 49, bh = idx / 49;
  int h = bh % 6, b = bh / 6;
  int n0 = nt * 64;
  int tid = threadIdx.x;
  int wid = tid >> 6, lane = tid & 63;
  int lrow = lane & 15, hi = lane >> 4, lk = hi * 8;
  {
    // head-major K: fully contiguous 8KB block
    int row = tid >> 1, koff = (tid & 1) * 16;
    const bf16* src = k_lowH + (((long)b * 6 + h) * 128 + row) * 32 + koff;
    *(bf16x8*)&Ks[row][koff] = *(const bf16x8*)src;
    *(bf16x8*)&Ks[row][koff + 8] = *(const bf16x8*)(src + 8);
  }
  {
    int row = tid >> 3, koff = (tid & 7) * 16;
    const bf16* src = v_lowT + ((long)b * 192 + h * 32 + row) * 128 + koff;
    *(bf16x8*)&Vs[row][koff] = *(const bf16x8*)src;
    *(bf16x8*)&Vs[row][koff + 8] = *(const bf16x8*)(src + 8);
  }
  int nrow = n0 + wid * 16 + lrow;
  bf16x8 qf = *(const bf16x8*)(q + ((long)b * NSEQ + nrow) * 192 + h * 32 + lk);
  __syncthreads();
  f32x4 zero = {0.f, 0.f, 0.f, 0.f};
  f32x4 s[8];
  // swapped: D[k][q] — lane's q-row = lrow (fixed), k = 16f + hi*4 + rr
  for (int f = 0; f < 8; f++) {
    bf16x8 kf = *(bf16x8*)&Ks[16 * f + lrow][lk];
    s[f] = MFMA16(kf, qf, zero);
  }
  float m = s[0][0];
  for (int f = 0; f < 8; f++) for (int rr = 0; rr < 4; rr++) m = fmaxf(m, s[f][rr]);
  m = fmaxf(m, __shfl_xor(m, 16));
  m = fmaxf(m, __shfl_xor(m, 32));
  float sum = 0.f;
  for (int f = 0; f < 8; f++) for (int rr = 0; rr < 4; rr++) {
    float p = __expf(s[f][rr] - m);
    s[f][rr] = p; sum += p;
  }
  sum += __shfl_xor(sum, 16);
  sum += __shfl_xor(sum, 32);
  float inv = 1.0f / sum;
  for (int f = 0; f < 8; f++) {
    bf16x4 pv;
    for (int rr = 0; rr < 4; rr++) pv[rr] = (bf16)(s[f][rr] * inv);
    *(bf16x4*)&Ps[wid][lrow][16 * f + hi * 4] = pv;
  }
  __syncthreads();
  f32x4 o[2];
  o[0] = zero; o[1] = zero;
  for (int ks = 0; ks < 4; ks++) {
    bf16x8 pf = *(bf16x8*)&Ps[wid][lrow][ks * 32 + lk];
    for (int j = 0; j < 2; j++) {
      bf16x8 vf = *(bf16x8*)&Vs[16 * j + lrow][ks * 32 + lk];
      o[j] = MFMA16(pf, vf, o[j]);
    }
  }
  // O store via wave-private Ps[wid] bounce -> one bf16x8 (16B) store per lane, 64B runs per row
  for (int j = 0; j < 2; j++)
    for (int rr = 0; rr < 4; rr++)
      Ps[wid][hi * 4 + rr][16 * j + lrow] = (bf16)o[j][rr];
  // wave-internal LDS ordering: compiler inserts lgkmcnt before the read below
  {
    int row_off = lane >> 2, ch = lane & 3;
    bf16x8 vv = *(bf16x8*)&Ps[wid][row_off][ch * 8];
    *(bf16x8*)(out_att + ((long)b * NSEQ + n0 + wid * 16 + row_off) * 192 + h * 32 + ch * 8) = vv;
  }
}

// ---------------- proj GEMM full-N: out(128 rows, all 192 cols) fp32; projw LDS-resident -----------
__launch_bounds__(256)
__global__ void k_proj(const bf16* __restrict__ oa, const bf16* __restrict__ projw,
                       const float* __restrict__ proj_b, float* __restrict__ out) {
  __shared__ bf16 As[128][104];
  __shared__ bf16 Bs[192][200];
  long g0 = (long)blockIdx.x * 128;
  int tid = threadIdx.x;
  int wid = tid >> 6, lane = tid & 63;
  int lrow = lane & 15, lk = (lane >> 4) * 8;
  {
    int koff = (tid & 3) * 48;
    for (int r0 = 0; r0 < 192; r0 += 64) {
      int row = r0 + (tid >> 2);
      const bf16* Bp = projw + (long)row * 192 + koff;
      for (int m = 0; m < 6; m++)
        *(bf16x8*)&Bs[row][koff + 8 * m] = *(const bf16x8*)(Bp + 8 * m);
    }
  }
  int arow = tid >> 1, half = tid & 1;
  const bf16* Ap = oa + (g0 + arow) * 192 + half * 48;
  f32x4 zero = {0.f, 0.f, 0.f, 0.f};
  f32x4 acc[2][12];
  for (int i = 0; i < 2; i++) for (int j = 0; j < 12; j++) acc[i][j] = zero;
  for (int k0 = 0; k0 < 192; k0 += 96) {
    for (int m = 0; m < 6; m++)
      *(bf16x8*)&As[arow][half * 48 + 8 * m] = *(const bf16x8*)(Ap + k0 + 8 * m);
    __syncthreads();
    for (int ks = 0; ks < 3; ks++) {
      bf16x8 af[2];
      for (int i = 0; i < 2; i++) af[i] = *(bf16x8*)&As[wid * 32 + 16 * i + lrow][ks * 32 + lk];
      for (int j = 0; j < 12; j++) {
        bf16x8 bv = *(bf16x8*)&Bs[16 * j + lrow][k0 + ks * 32 + lk];
        acc[0][j] = MFMA16(af[0], bv, acc[0][j]);
        acc[1][j] = MFMA16(af[1], bv, acc[1][j]);
      }
    }
    __syncthreads();
  }
  for (int i = 0; i < 2; i++) for (int j = 0; j < 12; j++) for (int rr = 0; rr < 4; rr++) {
    long grow = g0 + wid * 32 + 16 * i + (lane >> 4) * 4 + rr;
    int c = 16 * j + lrow;
    out[grow * 192 + c] = acc[i][j][rr] + proj_b[c];
  }
}

extern "C" void kernel_launch(void* const* d_in, const int* in_sizes, int n_in,
                              void* d_out, int out_size, void* d_ws, size_t ws_size,
                              hipStream_t stream) {
  const float* x      = (const float*)d_in[0];
  const float* qkv_w  = (const float*)d_in[1];
  const float* qkv_b  = (const float*)d_in[2];
  const float* E_w    = (const float*)d_in[3];
  const float* E_b    = (const float*)d_in[4];
  const float* F_w    = (const float*)d_in[5];
  const float* F_b    = (const float*)d_in[6];
  const float* proj_w = (const float*)d_in[7];
  const float* proj_b = (const float*)d_in[8];
  float* out = (float*)d_out;

  char* ws = (char*)d_ws;
  size_t off = 0;
  auto alloc = [&](size_t bytes) { char* p = ws + off; off += (bytes + 255) & ~(size_t)255; return p; };
  bf16* qkvw     = (bf16*)alloc((size_t)110592 * 2);
  bf16* EF       = (bf16*)alloc((size_t)802816 * 2);
  bf16* projw    = (bf16*)alloc((size_t)36864 * 2);
  float* rowsums = (float*)alloc((size_t)256 * 4);
  bf16* xmT      = (bf16*)alloc((size_t)32 * 192 * NSEQ * 2);   // reused as out_att after xlow
  bf16* q        = (bf16*)alloc((size_t)32 * NSEQ * 192 * 2);   // live xTq -> attn (no alias)
  float* partial = (float*)alloc((size_t)224 * 49152 * 4);      // 44 MB
  bf16* el_fl    = (bf16*)alloc((size_t)32 * 256 * 192 * 2);
  bf16* k_lowH   = (bf16*)alloc((size_t)32 * 6 * 128 * 32 * 2);
  bf16* v_lowT   = (bf16*)alloc((size_t)32 * 192 * 128 * 2);
  bf16* out_att  = xmT;

  k_prep<<<dim3(736), dim3(256), 0, stream>>>(qkv_w, E_w, F_w, proj_w, qkvw, EF, projw, rowsums);
  k_xTq<<<dim3(32 * 49), dim3(256), 0, stream>>>(x, qkvw, qkv_b, xmT, q);
  k_xlow<<<dim3(224), dim3(512), 0, stream>>>(EF, xmT, partial);
  k_reduce<<<dim3(1536), dim3(256), 0, stream>>>(partial, el_fl);
  k_lowproj<<<dim3(384), dim3(256), 0, stream>>>(el_fl, qkvw, qkv_b, E_b, F_b, rowsums, k_lowH, v_lowT);
  k_attn<<<dim3(32 * 6 * 49), dim3(256), 0, stream>>>(q, k_lowH, v_lowT, out_att);
  k_proj<<<dim3(784), dim3(256), 0, stream>>>(out_att, projw, proj_b, out);
}